// Round 1
// baseline (3814.888 us; speedup 1.0000x reference)
//
#include <hip/hip_runtime.h>
#include <math.h>

#define NN 10000
#define NE 160000
#define NRBF 50
#define HIDN 64
#define WNUM 2304
#define EPSV 1e-5f

// scales
#define A_P1 0.125f                  // 1/sqrt(2*32)
#define A_P2 0.17677669529663687f    // 1/sqrt(2*16)
#define A_P3 0.125f
#define A_P4 0.17677669529663687f
#define INV_SQRT3 0.5773502691896258f
#define INV_SQRT_M0 0.17677669529663687f  // 1/sqrt(32)
#define INV_SQRT_M1 0.25f                  // 1/sqrt(16)

__device__ __forceinline__ float dot64(const float* h2, const float* __restrict__ wr) {
  float p0 = 0.f, p1 = 0.f, p2 = 0.f, p3 = 0.f;
#pragma unroll
  for (int k = 0; k < 64; k += 4) {
    p0 += h2[k + 0] * wr[k + 0];
    p1 += h2[k + 1] * wr[k + 1];
    p2 += h2[k + 2] * wr[k + 2];
    p3 += h2[k + 3] * wr[k + 3];
  }
  return (p0 + p1) + (p2 + p3);
}

__global__ void transpose_w3(const float* __restrict__ W3, float* __restrict__ W3T) {
  int idx = blockIdx.x * 256 + threadIdx.x;
  if (idx < 64 * WNUM) {
    int j = idx >> 6, k = idx & 63;
    W3T[idx] = W3[k * WNUM + j];  // W3T[j][k]
  }
}

__global__ __launch_bounds__(256, 2) void edge_kernel(
    const float* __restrict__ h, const int* __restrict__ eidx,
    const float* __restrict__ esh, const float* __restrict__ ef,
    const float* __restrict__ W1, const float* __restrict__ b1,
    const float* __restrict__ W2, const float* __restrict__ b2,
    const float* __restrict__ b3, const float* __restrict__ W3T,
    float* __restrict__ agg, float* __restrict__ cnt) {
  __shared__ float h1s[64][256];  // 64 KB: layer-1 activations, lane-major (conflict-free)
  const int tid = threadIdx.x;
  const int e = blockIdx.x * 256 + tid;  // 160000 = 625*256 exact
  if (e >= NE) return;

  // ---- MLP layer 1: 50 -> 64, silu ----
  float acc[64];
#pragma unroll
  for (int k = 0; k < 64; k++) acc[k] = b1[k];
  const float* efr = ef + (long)e * NRBF;
#pragma unroll 1
  for (int i = 0; i < NRBF; i++) {
    float efi = efr[i];
#pragma unroll
    for (int k = 0; k < 64; k++) acc[k] += efi * W1[i * 64 + k];
  }
#pragma unroll
  for (int k = 0; k < 64; k++) {
    float x = acc[k];
    h1s[k][tid] = x / (1.f + __expf(-x));
  }

  // ---- MLP layer 2: 64 -> 64, silu ----
#pragma unroll
  for (int k = 0; k < 64; k++) acc[k] = b2[k];
#pragma unroll 1
  for (int i = 0; i < 64; i++) {
    float hi = h1s[i][tid];
#pragma unroll
    for (int k = 0; k < 64; k++) acc[k] += hi * W2[i * 64 + k];
  }
  float h2[64];
#pragma unroll
  for (int k = 0; k < 64; k++) {
    float x = acc[k];
    h2[k] = x / (1.f + __expf(-x));
  }

  // ---- per-edge geometric data ----
  const int src = eidx[e];
  const int dst = eidx[NE + e];
  const float* hs = h + (long)src * 80;
  float y0 = esh[e * 4 + 0];
  float y1x = esh[e * 4 + 1], y1y = esh[e * 4 + 2], y1z = esh[e * 4 + 3];

  float m0a[32], m1a[48], t3[16];
#pragma unroll
  for (int w = 0; w < 32; w++) m0a[w] = 0.f;
#pragma unroll
  for (int c = 0; c < 48; c++) m1a[c] = 0.f;
#pragma unroll
  for (int w = 0; w < 16; w++) t3[w] = 0.f;

  // ---- region w1: j in [0,1024), u<32, w<32 : m0[w] += A_P1*(s0[u]*y0)*w1[u,w]
#pragma unroll 1
  for (int u = 0; u < 32; u++) {
    float a0u = A_P1 * y0 * hs[u];
    const float* wr = W3T + (u * 32) * 64;
    const float* br = b3 + u * 32;
#pragma unroll
    for (int w = 0; w < 32; w++) {
      float v = br[w] + dot64(h2, wr + w * 64);
      m0a[w] += a0u * v;
    }
  }

  // ---- region w2: j in [1024,1280), u<16, w<16 : m1[w,i] += A_P2*(s1[u,i]*y0)*w2[u,w]
#pragma unroll 1
  for (int u = 0; u < 16; u++) {
    float c0 = A_P2 * y0 * hs[32 + u * 3 + 0];
    float c1 = A_P2 * y0 * hs[32 + u * 3 + 1];
    float c2 = A_P2 * y0 * hs[32 + u * 3 + 2];
    const float* wr = W3T + (1024 + u * 16) * 64;
    const float* br = b3 + 1024 + u * 16;
#pragma unroll
    for (int w = 0; w < 16; w++) {
      float v = br[w] + dot64(h2, wr + w * 64);
      m1a[w * 3 + 0] += c0 * v;
      m1a[w * 3 + 1] += c1 * v;
      m1a[w * 3 + 2] += c2 * v;
    }
  }

  // ---- region w3: j in [1280,1792), u<32, w<16 : t3[w] += A_P3*s0[u]*w3[u,w]  (×y1[i] later)
#pragma unroll 1
  for (int u = 0; u < 32; u++) {
    float s0u = A_P3 * hs[u];
    const float* wr = W3T + (1280 + u * 16) * 64;
    const float* br = b3 + 1280 + u * 16;
#pragma unroll
    for (int w = 0; w < 16; w++) {
      float v = br[w] + dot64(h2, wr + w * 64);
      t3[w] += s0u * v;
    }
  }

  // ---- region w4: j in [1792,2304), u<16, w<32 : m0[w] += A_P4*d11[u]*w4[u,w]
#pragma unroll 1
  for (int u = 0; u < 16; u++) {
    float d = A_P4 * INV_SQRT3 *
              (hs[32 + u * 3] * y1x + hs[33 + u * 3] * y1y + hs[34 + u * 3] * y1z);
    const float* wr = W3T + (1792 + u * 32) * 64;
    const float* br = b3 + 1792 + u * 32;
#pragma unroll
    for (int w = 0; w < 32; w++) {
      float v = br[w] + dot64(h2, wr + w * 64);
      m0a[w] += d * v;
    }
  }

  // fold t3 (w3 region) into m1 with y1[i]
#pragma unroll
  for (int w = 0; w < 16; w++) {
    m1a[w * 3 + 0] += y1x * t3[w];
    m1a[w * 3 + 1] += y1y * t3[w];
    m1a[w * 3 + 2] += y1z * t3[w];
  }

  // ---- scatter (mean numerator + count) ----
  float* ar = agg + (long)dst * 80;
#pragma unroll
  for (int w = 0; w < 32; w++) atomicAdd(ar + w, m0a[w]);
#pragma unroll
  for (int c = 0; c < 48; c++) atomicAdd(ar + 32 + c, m1a[c]);
  atomicAdd(cnt + dst, 1.0f);
}

__global__ void node_a(const float* __restrict__ h, const float* __restrict__ A0,
                       const float* __restrict__ A1p, const float* __restrict__ agg,
                       const float* __restrict__ cnt, float* __restrict__ outpre,
                       float* __restrict__ stats) {
  __shared__ float red[80];
  const int tid = threadIdx.x;
  const int n = blockIdx.x * 256 + tid;
  if (tid < 80) red[tid] = 0.f;
  __syncthreads();
  if (n < NN) {
    const float* hr = h + (long)n * 80;
    const float* ar = agg + (long)n * 80;
    float inv = 1.f / fmaxf(cnt[n], 1.f);
    float x0[32];
#pragma unroll
    for (int w = 0; w < 32; w++) x0[w] = 0.f;
#pragma unroll 1
    for (int u = 0; u < 32; u++) {
      float hu = hr[u];
#pragma unroll
      for (int w = 0; w < 32; w++) x0[w] += hu * A0[u * 32 + w];
    }
#pragma unroll
    for (int w = 0; w < 32; w++) x0[w] = x0[w] * INV_SQRT_M0 + ar[w] * inv;

    float x1[48];
#pragma unroll
    for (int c = 0; c < 48; c++) x1[c] = 0.f;
#pragma unroll 1
    for (int u = 0; u < 16; u++) {
      float a = hr[32 + u * 3], b_ = hr[33 + u * 3], c_ = hr[34 + u * 3];
#pragma unroll
      for (int w = 0; w < 16; w++) {
        float Aw = A1p[u * 16 + w];
        x1[w * 3 + 0] += a * Aw;
        x1[w * 3 + 1] += b_ * Aw;
        x1[w * 3 + 2] += c_ * Aw;
      }
    }
#pragma unroll
    for (int c = 0; c < 48; c++) x1[c] = x1[c] * INV_SQRT_M1 + ar[32 + c] * inv;

    float* opr = outpre + (long)n * 80;
#pragma unroll
    for (int w = 0; w < 32; w++) opr[w] = x0[w];
#pragma unroll
    for (int c = 0; c < 48; c++) opr[32 + c] = x1[c];

#pragma unroll
    for (int w = 0; w < 32; w++) {
      atomicAdd(&red[w], x0[w]);
      atomicAdd(&red[32 + w], x0[w] * x0[w]);
    }
#pragma unroll
    for (int u = 0; u < 16; u++) {
      float s = x1[u * 3] * x1[u * 3] + x1[u * 3 + 1] * x1[u * 3 + 1] +
                x1[u * 3 + 2] * x1[u * 3 + 2];
      atomicAdd(&red[64 + u], s);
    }
  }
  __syncthreads();
  if (tid < 80) atomicAdd(&stats[tid], red[tid]);
}

__global__ void node_b(const float* __restrict__ outpre, const float* __restrict__ stats,
                       const float* __restrict__ bnw0, const float* __restrict__ bnb0,
                       const float* __restrict__ bnw1, const float* __restrict__ h,
                       float* __restrict__ out) {
  int idx = blockIdx.x * 256 + threadIdx.x;
  if (idx >= NN * 80) return;
  int c = idx % 80;
  float v = outpre[idx];
  const float invN = 1.f / NN;
  float o;
  if (c < 32) {
    float mu = stats[c] * invN;
    float var = stats[32 + c] * invN - mu * mu;
    o = (v - mu) * rsqrtf(var + EPSV) * bnw0[c] + bnb0[c];
  } else {
    int u = (c - 32) / 3;
    float nr = stats[64 + u] * invN;
    o = v * rsqrtf(nr + EPSV) * bnw1[u];
  }
  out[idx] = o + h[idx];
}

extern "C" void kernel_launch(void* const* d_in, const int* in_sizes, int n_in,
                              void* d_out, int out_size, void* d_ws, size_t ws_size,
                              hipStream_t stream) {
  const float* h   = (const float*)d_in[0];
  const int*  eidx = (const int*)d_in[1];
  const float* esh = (const float*)d_in[2];
  const float* ef  = (const float*)d_in[3];
  const float* W1  = (const float*)d_in[4];
  const float* b1  = (const float*)d_in[5];
  const float* W2  = (const float*)d_in[6];
  const float* b2  = (const float*)d_in[7];
  const float* W3  = (const float*)d_in[8];
  const float* b3  = (const float*)d_in[9];
  const float* A0  = (const float*)d_in[10];
  const float* A1p = (const float*)d_in[11];
  const float* bnw0 = (const float*)d_in[12];
  const float* bnb0 = (const float*)d_in[13];
  const float* bnw1 = (const float*)d_in[14];
  float* out = (float*)d_out;

  float* ws = (float*)d_ws;
  float* agg    = ws;            // 800000
  float* cnt    = ws + 800000;   // 10000
  float* stats  = ws + 810000;   // 80
  float* outpre = ws + 810080;   // 800000
  float* W3T    = ws + 1610080;  // 147456

  // zero accumulators (agg + cnt + stats)
  hipMemsetAsync(agg, 0, (size_t)810080 * sizeof(float), stream);

  transpose_w3<<<(64 * WNUM + 255) / 256, 256, 0, stream>>>(W3, W3T);
  edge_kernel<<<NE / 256, 256, 0, stream>>>(h, eidx, esh, ef, W1, b1, W2, b2, b3, W3T,
                                            agg, cnt);
  node_a<<<(NN + 255) / 256, 256, 0, stream>>>(h, A0, A1p, agg, cnt, outpre, stats);
  node_b<<<(NN * 80 + 255) / 256, 256, 0, stream>>>(outpre, stats, bnw0, bnb0, bnw1, h,
                                                    out);
}

// Round 2
// 606.393 us; speedup vs baseline: 6.2911x; 6.2911x over previous
//
#include <hip/hip_runtime.h>
#include <math.h>

#define NN 10000
#define NE 160000
#define NRBF 50
#define WNUM 2304
#define EPSV 1e-5f

#define A_P1 0.125f
#define A_P2 0.17677669529663687f
#define A_P3 0.125f
#define A_P4 0.17677669529663687f
#define INV_SQRT3 0.5773502691896258f
#define INV_SQRT_M0 0.17677669529663687f
#define INV_SQRT_M1 0.25f

typedef __attribute__((ext_vector_type(8))) short bf16x8;
typedef __attribute__((ext_vector_type(4))) float f32x4;
typedef __attribute__((ext_vector_type(4))) int i32x4;

#define MFMA16(a, b, c) __builtin_amdgcn_mfma_f32_16x16x32_bf16(a, b, c, 0, 0, 0)

__device__ __forceinline__ short f2bf(float x) {
  unsigned u = __float_as_uint(x);
  unsigned r = (u + 0x7fffu + ((u >> 16) & 1u)) >> 16;
  return (short)r;
}

// ---- weight prep: transpose + bf16 convert ----
__global__ void prep_weights(const float* __restrict__ W1, const float* __restrict__ W2,
                             const float* __restrict__ W3, short* __restrict__ W1T,
                             short* __restrict__ W2T, short* __restrict__ W3T) {
  int idx = blockIdx.x * 256 + threadIdx.x;
  if (idx < WNUM * 64) {
    int j = idx >> 6, k = idx & 63;
    W3T[idx] = f2bf(W3[k * WNUM + j]);  // W3T[j][k]
  } else if (idx < WNUM * 64 + 4096) {
    int t = idx - WNUM * 64;
    int j = t >> 6, k = t & 63;
    W1T[t] = f2bf(k < NRBF ? W1[k * 64 + j] : 0.f);
  } else if (idx < WNUM * 64 + 8192) {
    int t = idx - WNUM * 64 - 4096;
    int j = t >> 6, k = t & 63;
    W2T[t] = f2bf(W2[k * 64 + j]);
  }
}

// compute v(e, j-tile) fragment: 2 MFMA over K=64 + bias
#define TILE_V(JT, V)                                                   \
  {                                                                     \
    const short* wb = W3T + ((JT) * 16 + lr) * 64 + lg * 8;             \
    bf16x8 b0 = *(const bf16x8*)wb;                                     \
    bf16x8 b1f = *(const bf16x8*)(wb + 32);                             \
    f32x4 d = {0.f, 0.f, 0.f, 0.f};                                     \
    d = MFMA16(a0, b0, d);                                              \
    d = MFMA16(a1, b1f, d);                                             \
    float bias = b3s[(JT) * 16 + lr];                                   \
    V[0] = d[0] + bias; V[1] = d[1] + bias;                             \
    V[2] = d[2] + bias; V[3] = d[3] + bias;                             \
  }

__global__ __launch_bounds__(256, 2) void edge_kernel(
    const float* __restrict__ h, const int* __restrict__ eidx,
    const float* __restrict__ esh, const float* __restrict__ ef,
    const short* __restrict__ W1T, const float* __restrict__ b1,
    const short* __restrict__ W2T, const float* __restrict__ b2,
    const short* __restrict__ W3T, const float* __restrict__ b3,
    float* __restrict__ agg, float* __restrict__ cnt) {
  __shared__ short efs[64 * 72];
  __shared__ short h1s[64 * 72];
  __shared__ short h2s[64 * 72];
  __shared__ float b3s[WNUM];
  __shared__ float a0s[32 * 64];   // A_P1*y0*s0[u]
  __shared__ float s0c[32 * 64];   // A_P3*s0[u]
  __shared__ float cYs[3 * 16 * 64];  // A_P2*y0*s1[u][i]
  __shared__ float d4s[16 * 64];   // A_P4*inv_sqrt3*(s1[u].y1)
  __shared__ float y1s[3 * 64];
  __shared__ float b1s[64], b2s[64];
  __shared__ int dsts[64];

  const int tid = threadIdx.x;
  const int e0 = blockIdx.x * 64;

  // ---- Phase A: staging ----
  for (int idx = tid; idx < 64 * 64; idx += 256) {
    int e = idx >> 6, k = idx & 63;
    float v = (k < NRBF) ? ef[(long)(e0 + e) * NRBF + k] : 0.f;
    efs[e * 72 + k] = f2bf(v);
  }
  for (int idx = tid; idx < WNUM; idx += 256) b3s[idx] = b3[idx];
  if (tid < 64) { b1s[tid] = b1[tid]; b2s[tid] = b2[tid]; }
  {
    int e = tid >> 2, q = tid & 3;
    int ge = e0 + e;
    int src = eidx[ge];
    float y0 = esh[ge * 4 + 0];
    float y1x = esh[ge * 4 + 1], y1y = esh[ge * 4 + 2], y1z = esh[ge * 4 + 3];
    const float* hs = h + (long)src * 80;
    for (int u = q; u < 32; u += 4) {
      float s = hs[u];
      a0s[u * 64 + e] = A_P1 * y0 * s;
      s0c[u * 64 + e] = A_P3 * s;
    }
    for (int u = q; u < 16; u += 4) {
      float sx = hs[32 + u * 3], sy = hs[33 + u * 3], sz = hs[34 + u * 3];
      cYs[(0 * 16 + u) * 64 + e] = A_P2 * y0 * sx;
      cYs[(1 * 16 + u) * 64 + e] = A_P2 * y0 * sy;
      cYs[(2 * 16 + u) * 64 + e] = A_P2 * y0 * sz;
      d4s[u * 64 + e] = A_P4 * INV_SQRT3 * (sx * y1x + sy * y1y + sz * y1z);
    }
    if (q == 0) {
      y1s[0 * 64 + e] = y1x; y1s[1 * 64 + e] = y1y; y1s[2 * 64 + e] = y1z;
      dsts[e] = eidx[NE + ge];
    }
  }
  __syncthreads();

  const int wid = tid >> 6, l = tid & 63;
  const int er = wid * 16;
  const int lr = l & 15, lg = l >> 4;

  // ---- Phase B: MLP layer 1 (K=64 padded) ----
  {
    bf16x8 a0 = *(const bf16x8*)&efs[(er + lr) * 72 + lg * 8];
    bf16x8 a1 = *(const bf16x8*)&efs[(er + lr) * 72 + 32 + lg * 8];
#pragma unroll
    for (int jt = 0; jt < 4; ++jt) {
      const short* wb = W1T + (jt * 16 + lr) * 64 + lg * 8;
      bf16x8 b0 = *(const bf16x8*)wb;
      bf16x8 b1f = *(const bf16x8*)(wb + 32);
      f32x4 d = {0.f, 0.f, 0.f, 0.f};
      d = MFMA16(a0, b0, d);
      d = MFMA16(a1, b1f, d);
      float bias = b1s[jt * 16 + lr];
#pragma unroll
      for (int r = 0; r < 4; ++r) {
        float x = d[r] + bias;
        x = x / (1.f + __expf(-x));
        h1s[(er + lg * 4 + r) * 72 + jt * 16 + lr] = f2bf(x);
      }
    }
  }
  __syncthreads();

  // ---- MLP layer 2 ----
  {
    bf16x8 a0 = *(const bf16x8*)&h1s[(er + lr) * 72 + lg * 8];
    bf16x8 a1 = *(const bf16x8*)&h1s[(er + lr) * 72 + 32 + lg * 8];
#pragma unroll
    for (int jt = 0; jt < 4; ++jt) {
      const short* wb = W2T + (jt * 16 + lr) * 64 + lg * 8;
      bf16x8 b0 = *(const bf16x8*)wb;
      bf16x8 b1f = *(const bf16x8*)(wb + 32);
      f32x4 d = {0.f, 0.f, 0.f, 0.f};
      d = MFMA16(a0, b0, d);
      d = MFMA16(a1, b1f, d);
      float bias = b2s[jt * 16 + lr];
#pragma unroll
      for (int r = 0; r < 4; ++r) {
        float x = d[r] + bias;
        x = x / (1.f + __expf(-x));
        h2s[(er + lg * 4 + r) * 72 + jt * 16 + lr] = f2bf(x);
      }
    }
  }
  __syncthreads();

  // ---- Phase C: layer 3 GEMM + fold, fused per j-tile ----
  bf16x8 a0 = *(const bf16x8*)&h2s[(er + lr) * 72 + lg * 8];
  bf16x8 a1 = *(const bf16x8*)&h2s[(er + lr) * 72 + 32 + lg * 8];
  f32x4 y1r0 = *(const f32x4*)&y1s[0 * 64 + er + lg * 4];
  f32x4 y1r1 = *(const f32x4*)&y1s[1 * 64 + er + lg * 4];
  f32x4 y1r2 = *(const f32x4*)&y1s[2 * 64 + er + lg * 4];
  i32x4 dd = *(const i32x4*)&dsts[er + lg * 4];

  f32x4 m0f0 = {0.f, 0.f, 0.f, 0.f}, m0f1 = {0.f, 0.f, 0.f, 0.f};
  f32x4 m1f0 = {0.f, 0.f, 0.f, 0.f}, m1f1 = {0.f, 0.f, 0.f, 0.f},
        m1f2 = {0.f, 0.f, 0.f, 0.f};

  // region w1: j-tiles [0,64), u = jt>>1, m0[w] += a0s[u]*v
#pragma unroll 2
  for (int jp = 0; jp < 32; ++jp) {
    f32x4 c = *(const f32x4*)&a0s[jp * 64 + er + lg * 4];
    f32x4 v;
    TILE_V(jp * 2, v);
#pragma unroll
    for (int r = 0; r < 4; ++r) m0f0[r] += c[r] * v[r];
    f32x4 v2;
    TILE_V(jp * 2 + 1, v2);
#pragma unroll
    for (int r = 0; r < 4; ++r) m0f1[r] += c[r] * v2[r];
  }

  // region w2: j-tiles [64,80), u = jt-64, m1[w][i] += cYs[i][u]*v
#pragma unroll 2
  for (int u = 0; u < 16; ++u) {
    f32x4 v;
    TILE_V(64 + u, v);
    f32x4 c0 = *(const f32x4*)&cYs[(0 * 16 + u) * 64 + er + lg * 4];
    f32x4 c1 = *(const f32x4*)&cYs[(1 * 16 + u) * 64 + er + lg * 4];
    f32x4 c2 = *(const f32x4*)&cYs[(2 * 16 + u) * 64 + er + lg * 4];
#pragma unroll
    for (int r = 0; r < 4; ++r) {
      m1f0[r] += c0[r] * v[r];
      m1f1[r] += c1[r] * v[r];
      m1f2[r] += c2[r] * v[r];
    }
  }

  // region w3: j-tiles [80,112), u = jt-80, m1[w][i] += s0c[u]*y1[i]*v
#pragma unroll 2
  for (int u = 0; u < 32; ++u) {
    f32x4 v;
    TILE_V(80 + u, v);
    f32x4 c = *(const f32x4*)&s0c[u * 64 + er + lg * 4];
#pragma unroll
    for (int r = 0; r < 4; ++r) {
      float t = c[r] * v[r];
      m1f0[r] += t * y1r0[r];
      m1f1[r] += t * y1r1[r];
      m1f2[r] += t * y1r2[r];
    }
  }

  // region w4: j-tiles [112,144), u = (jt-112)>>1, m0[w] += d4s[u]*v
#pragma unroll 2
  for (int up = 0; up < 16; ++up) {
    f32x4 c = *(const f32x4*)&d4s[up * 64 + er + lg * 4];
    f32x4 v;
    TILE_V(112 + up * 2, v);
#pragma unroll
    for (int r = 0; r < 4; ++r) m0f0[r] += c[r] * v[r];
    f32x4 v2;
    TILE_V(112 + up * 2 + 1, v2);
#pragma unroll
    for (int r = 0; r < 4; ++r) m0f1[r] += c[r] * v2[r];
  }

  // ---- scatter ----
#pragma unroll
  for (int r = 0; r < 4; ++r) {
    float* base = agg + (long)dd[r] * 80;
    atomicAdd(base + lr, m0f0[r]);
    atomicAdd(base + 16 + lr, m0f1[r]);
    atomicAdd(base + 32 + lr * 3 + 0, m1f0[r]);
    atomicAdd(base + 32 + lr * 3 + 1, m1f1[r]);
    atomicAdd(base + 32 + lr * 3 + 2, m1f2[r]);
  }
  if (tid < 64) atomicAdd(cnt + dsts[tid], 1.0f);
}

__global__ void node_a(const float* __restrict__ h, const float* __restrict__ A0,
                       const float* __restrict__ A1p, const float* __restrict__ agg,
                       const float* __restrict__ cnt, float* __restrict__ outpre,
                       float* __restrict__ stats) {
  __shared__ float red[80];
  const int tid = threadIdx.x;
  const int n = blockIdx.x * 256 + tid;
  if (tid < 80) red[tid] = 0.f;
  __syncthreads();
  if (n < NN) {
    const float* hr = h + (long)n * 80;
    const float* ar = agg + (long)n * 80;
    float inv = 1.f / fmaxf(cnt[n], 1.f);
    float x0[32];
#pragma unroll
    for (int w = 0; w < 32; w++) x0[w] = 0.f;
#pragma unroll 1
    for (int u = 0; u < 32; u++) {
      float hu = hr[u];
#pragma unroll
      for (int w = 0; w < 32; w++) x0[w] += hu * A0[u * 32 + w];
    }
#pragma unroll
    for (int w = 0; w < 32; w++) x0[w] = x0[w] * INV_SQRT_M0 + ar[w] * inv;

    float x1[48];
#pragma unroll
    for (int c = 0; c < 48; c++) x1[c] = 0.f;
#pragma unroll 1
    for (int u = 0; u < 16; u++) {
      float a = hr[32 + u * 3], b_ = hr[33 + u * 3], c_ = hr[34 + u * 3];
#pragma unroll
      for (int w = 0; w < 16; w++) {
        float Aw = A1p[u * 16 + w];
        x1[w * 3 + 0] += a * Aw;
        x1[w * 3 + 1] += b_ * Aw;
        x1[w * 3 + 2] += c_ * Aw;
      }
    }
#pragma unroll
    for (int c = 0; c < 48; c++) x1[c] = x1[c] * INV_SQRT_M1 + ar[32 + c] * inv;

    float* opr = outpre + (long)n * 80;
#pragma unroll
    for (int w = 0; w < 32; w++) opr[w] = x0[w];
#pragma unroll
    for (int c = 0; c < 48; c++) opr[32 + c] = x1[c];

#pragma unroll
    for (int w = 0; w < 32; w++) {
      atomicAdd(&red[w], x0[w]);
      atomicAdd(&red[32 + w], x0[w] * x0[w]);
    }
#pragma unroll
    for (int u = 0; u < 16; u++) {
      float s = x1[u * 3] * x1[u * 3] + x1[u * 3 + 1] * x1[u * 3 + 1] +
                x1[u * 3 + 2] * x1[u * 3 + 2];
      atomicAdd(&red[64 + u], s);
    }
  }
  __syncthreads();
  if (tid < 80) atomicAdd(&stats[tid], red[tid]);
}

__global__ void node_b(const float* __restrict__ outpre, const float* __restrict__ stats,
                       const float* __restrict__ bnw0, const float* __restrict__ bnb0,
                       const float* __restrict__ bnw1, const float* __restrict__ h,
                       float* __restrict__ out) {
  int idx = blockIdx.x * 256 + threadIdx.x;
  if (idx >= NN * 80) return;
  int c = idx % 80;
  float v = outpre[idx];
  const float invN = 1.f / NN;
  float o;
  if (c < 32) {
    float mu = stats[c] * invN;
    float var = stats[32 + c] * invN - mu * mu;
    o = (v - mu) * rsqrtf(var + EPSV) * bnw0[c] + bnb0[c];
  } else {
    int u = (c - 32) / 3;
    float nr = stats[64 + u] * invN;
    o = v * rsqrtf(nr + EPSV) * bnw1[u];
  }
  out[idx] = o + h[idx];
}

extern "C" void kernel_launch(void* const* d_in, const int* in_sizes, int n_in,
                              void* d_out, int out_size, void* d_ws, size_t ws_size,
                              hipStream_t stream) {
  const float* h    = (const float*)d_in[0];
  const int*   eidx = (const int*)d_in[1];
  const float* esh  = (const float*)d_in[2];
  const float* ef   = (const float*)d_in[3];
  const float* W1   = (const float*)d_in[4];
  const float* b1   = (const float*)d_in[5];
  const float* W2   = (const float*)d_in[6];
  const float* b2   = (const float*)d_in[7];
  const float* W3   = (const float*)d_in[8];
  const float* b3   = (const float*)d_in[9];
  const float* A0   = (const float*)d_in[10];
  const float* A1p  = (const float*)d_in[11];
  const float* bnw0 = (const float*)d_in[12];
  const float* bnb0 = (const float*)d_in[13];
  const float* bnw1 = (const float*)d_in[14];
  float* out = (float*)d_out;

  float* ws = (float*)d_ws;
  float* agg    = ws;             // 800000
  float* cnt    = ws + 800000;    // 10000
  float* stats  = ws + 810000;    // 80
  float* outpre = ws + 810080;    // 800000
  short* W3T    = (short*)(ws + 1610080);  // 147456 shorts
  short* W1T    = W3T + WNUM * 64;         // 4096 shorts
  short* W2T    = W1T + 4096;              // 4096 shorts

  hipMemsetAsync(agg, 0, (size_t)810080 * sizeof(float), stream);

  prep_weights<<<(WNUM * 64 + 8192 + 255) / 256, 256, 0, stream>>>(W1, W2, W3, W1T,
                                                                   W2T, W3T);
  edge_kernel<<<NE / 64, 256, 0, stream>>>(h, eidx, esh, ef, W1T, b1, W2T, b2, W3T, b3,
                                           agg, cnt);
  node_a<<<(NN + 255) / 256, 256, 0, stream>>>(h, A0, A1p, agg, cnt, outpre, stats);
  node_b<<<(NN * 80 + 255) / 256, 256, 0, stream>>>(outpre, stats, bnw0, bnb0, bnw1, h,
                                                    out);
}

// Round 3
// 234.675 us; speedup vs baseline: 16.2560x; 2.5840x over previous
//
#include <hip/hip_runtime.h>
#include <math.h>

#define NN 10000
#define NE 160000
#define NRBF 50
#define WNUM 2304
#define EPSV 1e-5f

#define A_P1 0.125f
#define A_P2 0.17677669529663687f
#define A_P3 0.125f
#define A_P4 0.17677669529663687f
#define INV_SQRT3 0.5773502691896258f
#define INV_SQRT_M0 0.17677669529663687f
#define INV_SQRT_M1 0.25f

typedef __attribute__((ext_vector_type(8))) short bf16x8;
typedef __attribute__((ext_vector_type(4))) float f32x4;
typedef __attribute__((ext_vector_type(4))) int i32x4;

#define MFMA16(a, b, c) __builtin_amdgcn_mfma_f32_16x16x32_bf16(a, b, c, 0, 0, 0)

__device__ __forceinline__ short f2bf(float x) {
  unsigned u = __float_as_uint(x);
  unsigned r = (u + 0x7fffu + ((u >> 16) & 1u)) >> 16;
  return (short)r;
}

// ---- weight prep: transpose + bf16 + fragment-order packing ----
// Packed layout per 16-col tile t: 1024 shorts = [chunk(2)][lane(64)][kk(8)].
// Lane l, chunk c holds B[row = t*16 + (l&15)][k = (l>>4)*8 + c*32 + kk].
__global__ void prep_weights(const float* __restrict__ W1, const float* __restrict__ W2,
                             const float* __restrict__ W3, short* __restrict__ W1P,
                             short* __restrict__ W2P, short* __restrict__ W3P) {
  int s = blockIdx.x * 256 + threadIdx.x;
  if (s < WNUM * 64) {
    int t = s >> 10, r = s & 1023;
    int ch = r >> 9, l = (r >> 3) & 63, kk = r & 7;
    int row = t * 16 + (l & 15);
    int k = ((l >> 4) << 3) + (ch << 5) + kk;
    W3P[s] = f2bf(W3[k * WNUM + row]);
  } else if (s < WNUM * 64 + 4096) {
    int s2 = s - WNUM * 64;
    int t = s2 >> 10, r = s2 & 1023;
    int ch = r >> 9, l = (r >> 3) & 63, kk = r & 7;
    int row = t * 16 + (l & 15);
    int k = ((l >> 4) << 3) + (ch << 5) + kk;
    W1P[s2] = f2bf(k < NRBF ? W1[k * 64 + row] : 0.f);
  } else if (s < WNUM * 64 + 8192) {
    int s2 = s - WNUM * 64 - 4096;
    int t = s2 >> 10, r = s2 & 1023;
    int ch = r >> 9, l = (r >> 3) & 63, kk = r & 7;
    int row = t * 16 + (l & 15);
    int k = ((l >> 4) << 3) + (ch << 5) + kk;
    W2P[s2] = f2bf(W2[k * 64 + row]);
  }
}

// v(e, j-tile): bias as MFMA C-init + 2 MFMA over K=64
#define TILE_V(JT, V)                                         \
  {                                                           \
    const short* wb = W3P + ((JT) << 10) + (l << 3);          \
    bf16x8 b0 = *(const bf16x8*)wb;                           \
    bf16x8 b1f = *(const bf16x8*)(wb + 512);                  \
    float bias = b3[((JT) << 4) + lr];                        \
    f32x4 d = {bias, bias, bias, bias};                       \
    d = MFMA16(a0, b0, d);                                    \
    V = MFMA16(a1, b1f, d);                                   \
  }

__global__ __launch_bounds__(256, 3) void edge_kernel(
    const float* __restrict__ h, const int* __restrict__ eidx,
    const float* __restrict__ esh, const float* __restrict__ ef,
    const short* __restrict__ W1P, const float* __restrict__ b1,
    const short* __restrict__ W2P, const float* __restrict__ b2,
    const short* __restrict__ W3P, const float* __restrict__ b3,
    float* __restrict__ agg, float* __restrict__ cnt) {
  __shared__ short buf0[64 * 72];  // efs, later reused as h2s
  __shared__ short h1s[64 * 72];
  __shared__ float a0s[32 * 64];      // A_P1*y0*s0[u]
  __shared__ float s0c[32 * 64];      // A_P3*s0[u]
  __shared__ float cYs[3 * 16 * 64];  // A_P2*y0*s1[u][i]
  __shared__ float d4s[16 * 64];      // A_P4*inv_sqrt3*(s1[u].y1)
  __shared__ float y1s[3 * 64];
  __shared__ float b1s[64], b2s[64];
  __shared__ int dsts[64];

  const int tid = threadIdx.x;
  const int e0 = blockIdx.x * 64;

  // ---- Phase A: staging ----
  for (int idx = tid; idx < 64 * 64; idx += 256) {
    int e = idx >> 6, k = idx & 63;
    float v = (k < NRBF) ? ef[(long)(e0 + e) * NRBF + k] : 0.f;
    buf0[e * 72 + k] = f2bf(v);
  }
  if (tid < 64) { b1s[tid] = b1[tid]; b2s[tid] = b2[tid]; }
  {
    int e = tid >> 2, q = tid & 3;
    int ge = e0 + e;
    int src = eidx[ge];
    float y0 = esh[ge * 4 + 0];
    float y1x = esh[ge * 4 + 1], y1y = esh[ge * 4 + 2], y1z = esh[ge * 4 + 3];
    const float* hs = h + (long)src * 80;
    for (int u = q; u < 32; u += 4) {
      float s = hs[u];
      a0s[u * 64 + e] = A_P1 * y0 * s;
      s0c[u * 64 + e] = A_P3 * s;
    }
    for (int u = q; u < 16; u += 4) {
      float sx = hs[32 + u * 3], sy = hs[33 + u * 3], sz = hs[34 + u * 3];
      cYs[(0 * 16 + u) * 64 + e] = A_P2 * y0 * sx;
      cYs[(1 * 16 + u) * 64 + e] = A_P2 * y0 * sy;
      cYs[(2 * 16 + u) * 64 + e] = A_P2 * y0 * sz;
      d4s[u * 64 + e] = A_P4 * INV_SQRT3 * (sx * y1x + sy * y1y + sz * y1z);
    }
    if (q == 0) {
      y1s[0 * 64 + e] = y1x; y1s[1 * 64 + e] = y1y; y1s[2 * 64 + e] = y1z;
      dsts[e] = eidx[NE + ge];
    }
  }
  __syncthreads();

  const int wid = tid >> 6, l = tid & 63;
  const int er = wid * 16;
  const int lr = l & 15, lg = l >> 4;
  const int row4 = er + lg * 4;

  // ---- MLP layer 1 (K=64 padded) ----
  {
    bf16x8 a0 = *(const bf16x8*)&buf0[(er + lr) * 72 + lg * 8];
    bf16x8 a1 = *(const bf16x8*)&buf0[(er + lr) * 72 + 32 + lg * 8];
#pragma unroll
    for (int jt = 0; jt < 4; ++jt) {
      const short* wb = W1P + (jt << 10) + (l << 3);
      bf16x8 b0 = *(const bf16x8*)wb;
      bf16x8 b1f = *(const bf16x8*)(wb + 512);
      float bias = b1s[jt * 16 + lr];
      f32x4 d = {bias, bias, bias, bias};
      d = MFMA16(a0, b0, d);
      d = MFMA16(a1, b1f, d);
#pragma unroll
      for (int r = 0; r < 4; ++r) {
        float x = d[r];
        x = x / (1.f + __expf(-x));
        h1s[(row4 + r) * 72 + jt * 16 + lr] = f2bf(x);
      }
    }
  }
  __syncthreads();

  // ---- MLP layer 2 (h2 -> buf0, aliasing dead efs) ----
  {
    bf16x8 a0 = *(const bf16x8*)&h1s[(er + lr) * 72 + lg * 8];
    bf16x8 a1 = *(const bf16x8*)&h1s[(er + lr) * 72 + 32 + lg * 8];
#pragma unroll
    for (int jt = 0; jt < 4; ++jt) {
      const short* wb = W2P + (jt << 10) + (l << 3);
      bf16x8 b0 = *(const bf16x8*)wb;
      bf16x8 b1f = *(const bf16x8*)(wb + 512);
      float bias = b2s[jt * 16 + lr];
      f32x4 d = {bias, bias, bias, bias};
      d = MFMA16(a0, b0, d);
      d = MFMA16(a1, b1f, d);
#pragma unroll
      for (int r = 0; r < 4; ++r) {
        float x = d[r];
        x = x / (1.f + __expf(-x));
        buf0[(row4 + r) * 72 + jt * 16 + lr] = f2bf(x);
      }
    }
  }
  __syncthreads();

  // ---- Phase C: layer-3 GEMM + fold, fused per j-tile ----
  bf16x8 a0 = *(const bf16x8*)&buf0[(er + lr) * 72 + lg * 8];
  bf16x8 a1 = *(const bf16x8*)&buf0[(er + lr) * 72 + 32 + lg * 8];
  f32x4 y1r0 = *(const f32x4*)&y1s[0 * 64 + row4];
  f32x4 y1r1 = *(const f32x4*)&y1s[1 * 64 + row4];
  f32x4 y1r2 = *(const f32x4*)&y1s[2 * 64 + row4];
  i32x4 dd = *(const i32x4*)&dsts[row4];

  f32x4 m0f0 = {0.f, 0.f, 0.f, 0.f}, m0f1 = {0.f, 0.f, 0.f, 0.f};
  f32x4 m1f0 = {0.f, 0.f, 0.f, 0.f}, m1f1 = {0.f, 0.f, 0.f, 0.f},
        m1f2 = {0.f, 0.f, 0.f, 0.f};

  // region w1: tiles [0,64), u = jp, m0 += a0s[u]*v
#pragma unroll 2
  for (int jp = 0; jp < 32; ++jp) {
    f32x4 c = *(const f32x4*)&a0s[jp * 64 + row4];
    f32x4 v, v2;
    TILE_V(jp * 2, v);
    TILE_V(jp * 2 + 1, v2);
#pragma unroll
    for (int r = 0; r < 4; ++r) {
      m0f0[r] += c[r] * v[r];
      m0f1[r] += c[r] * v2[r];
    }
  }

  // region w2: tiles [64,80), m1[w][i] += cYs[i][u]*v
#pragma unroll 4
  for (int u = 0; u < 16; ++u) {
    f32x4 v;
    TILE_V(64 + u, v);
    f32x4 c0 = *(const f32x4*)&cYs[(0 * 16 + u) * 64 + row4];
    f32x4 c1 = *(const f32x4*)&cYs[(1 * 16 + u) * 64 + row4];
    f32x4 c2 = *(const f32x4*)&cYs[(2 * 16 + u) * 64 + row4];
#pragma unroll
    for (int r = 0; r < 4; ++r) {
      m1f0[r] += c0[r] * v[r];
      m1f1[r] += c1[r] * v[r];
      m1f2[r] += c2[r] * v[r];
    }
  }

  // region w3: tiles [80,112), m1[w][i] += s0c[u]*y1[i]*v
#pragma unroll 4
  for (int u = 0; u < 32; ++u) {
    f32x4 v;
    TILE_V(80 + u, v);
    f32x4 c = *(const f32x4*)&s0c[u * 64 + row4];
#pragma unroll
    for (int r = 0; r < 4; ++r) {
      float t = c[r] * v[r];
      m1f0[r] += t * y1r0[r];
      m1f1[r] += t * y1r1[r];
      m1f2[r] += t * y1r2[r];
    }
  }

  // region w4: tiles [112,144), m0 += d4s[u]*v
#pragma unroll 2
  for (int up = 0; up < 16; ++up) {
    f32x4 c = *(const f32x4*)&d4s[up * 64 + row4];
    f32x4 v, v2;
    TILE_V(112 + up * 2, v);
    TILE_V(112 + up * 2 + 1, v2);
#pragma unroll
    for (int r = 0; r < 4; ++r) {
      m0f0[r] += c[r] * v[r];
      m0f1[r] += c[r] * v2[r];
    }
  }

  // ---- scatter ----
#pragma unroll
  for (int r = 0; r < 4; ++r) {
    float* base = agg + (long)dd[r] * 80;
    atomicAdd(base + lr, m0f0[r]);
    atomicAdd(base + 16 + lr, m0f1[r]);
    atomicAdd(base + 32 + lr * 3 + 0, m1f0[r]);
    atomicAdd(base + 32 + lr * 3 + 1, m1f1[r]);
    atomicAdd(base + 32 + lr * 3 + 2, m1f2[r]);
  }
  if (tid < 64) atomicAdd(cnt + dsts[tid], 1.0f);
}

__global__ __launch_bounds__(256) void node_a(
    const float* __restrict__ h, const float* __restrict__ A0,
    const float* __restrict__ A1p, const float* __restrict__ agg,
    const float* __restrict__ cnt, float* __restrict__ outpre,
    float* __restrict__ stats) {
  __shared__ float redw[4][80];
  const int tid = threadIdx.x;
  const int wid = tid >> 6, l = tid & 63;
  const int n = blockIdx.x * 256 + tid;
  float x0[32], x1[48];
#pragma unroll
  for (int w = 0; w < 32; w++) x0[w] = 0.f;
#pragma unroll
  for (int c = 0; c < 48; c++) x1[c] = 0.f;
  if (n < NN) {
    const float* hr = h + (long)n * 80;
    const float* ar = agg + (long)n * 80;
    float inv = 1.f / fmaxf(cnt[n], 1.f);
#pragma unroll 1
    for (int u = 0; u < 32; u++) {
      float hu = hr[u];
#pragma unroll
      for (int w = 0; w < 32; w++) x0[w] += hu * A0[u * 32 + w];
    }
#pragma unroll
    for (int w = 0; w < 32; w++) x0[w] = x0[w] * INV_SQRT_M0 + ar[w] * inv;
#pragma unroll 1
    for (int u = 0; u < 16; u++) {
      float a = hr[32 + u * 3], b_ = hr[33 + u * 3], c_ = hr[34 + u * 3];
#pragma unroll
      for (int w = 0; w < 16; w++) {
        float Aw = A1p[u * 16 + w];
        x1[w * 3 + 0] += a * Aw;
        x1[w * 3 + 1] += b_ * Aw;
        x1[w * 3 + 2] += c_ * Aw;
      }
    }
#pragma unroll
    for (int c = 0; c < 48; c++) x1[c] = x1[c] * INV_SQRT_M1 + ar[32 + c] * inv;
    float* opr = outpre + (long)n * 80;
#pragma unroll
    for (int w = 0; w < 32; w++) opr[w] = x0[w];
#pragma unroll
    for (int c = 0; c < 48; c++) opr[32 + c] = x1[c];
  }
  // wave butterfly reductions (all lanes participate; invalid lanes hold zeros)
#pragma unroll 1
  for (int c = 0; c < 32; ++c) {
    float s = x0[c];
#pragma unroll
    for (int m = 32; m >= 1; m >>= 1) s += __shfl_xor(s, m, 64);
    if (l == 0) redw[wid][c] = s;
  }
#pragma unroll 1
  for (int c = 0; c < 32; ++c) {
    float v = x0[c];
    float s = v * v;
#pragma unroll
    for (int m = 32; m >= 1; m >>= 1) s += __shfl_xor(s, m, 64);
    if (l == 0) redw[wid][32 + c] = s;
  }
#pragma unroll 1
  for (int u = 0; u < 16; ++u) {
    float s = x1[u * 3] * x1[u * 3] + x1[u * 3 + 1] * x1[u * 3 + 1] +
              x1[u * 3 + 2] * x1[u * 3 + 2];
#pragma unroll
    for (int m = 32; m >= 1; m >>= 1) s += __shfl_xor(s, m, 64);
    if (l == 0) redw[wid][64 + u] = s;
  }
  __syncthreads();
  if (tid < 80)
    atomicAdd(&stats[tid],
              redw[0][tid] + redw[1][tid] + redw[2][tid] + redw[3][tid]);
}

__global__ void node_b(const float* __restrict__ outpre, const float* __restrict__ stats,
                       const float* __restrict__ bnw0, const float* __restrict__ bnb0,
                       const float* __restrict__ bnw1, const float* __restrict__ h,
                       float* __restrict__ out) {
  int idx = blockIdx.x * 256 + threadIdx.x;
  if (idx >= NN * 80) return;
  int c = idx % 80;
  float v = outpre[idx];
  const float invN = 1.f / NN;
  float o;
  if (c < 32) {
    float mu = stats[c] * invN;
    float var = stats[32 + c] * invN - mu * mu;
    o = (v - mu) * rsqrtf(var + EPSV) * bnw0[c] + bnb0[c];
  } else {
    int u = (c - 32) / 3;
    float nr = stats[64 + u] * invN;
    o = v * rsqrtf(nr + EPSV) * bnw1[u];
  }
  out[idx] = o + h[idx];
}

extern "C" void kernel_launch(void* const* d_in, const int* in_sizes, int n_in,
                              void* d_out, int out_size, void* d_ws, size_t ws_size,
                              hipStream_t stream) {
  const float* h    = (const float*)d_in[0];
  const int*   eidx = (const int*)d_in[1];
  const float* esh  = (const float*)d_in[2];
  const float* ef   = (const float*)d_in[3];
  const float* W1   = (const float*)d_in[4];
  const float* b1   = (const float*)d_in[5];
  const float* W2   = (const float*)d_in[6];
  const float* b2   = (const float*)d_in[7];
  const float* W3   = (const float*)d_in[8];
  const float* b3   = (const float*)d_in[9];
  const float* A0   = (const float*)d_in[10];
  const float* A1p  = (const float*)d_in[11];
  const float* bnw0 = (const float*)d_in[12];
  const float* bnb0 = (const float*)d_in[13];
  const float* bnw1 = (const float*)d_in[14];
  float* out = (float*)d_out;

  float* ws = (float*)d_ws;
  float* agg    = ws;             // 800000
  float* cnt    = ws + 800000;    // 10000
  float* stats  = ws + 810000;    // 80
  float* outpre = ws + 810080;    // 800000
  short* W3P    = (short*)(ws + 1610080);  // 147456 shorts
  short* W1P    = W3P + WNUM * 64;         // 4096 shorts
  short* W2P    = W1P + 4096;              // 4096 shorts

  hipMemsetAsync(agg, 0, (size_t)810080 * sizeof(float), stream);

  prep_weights<<<(WNUM * 64 + 8192 + 255) / 256, 256, 0, stream>>>(W1, W2, W3, W1P,
                                                                   W2P, W3P);
  edge_kernel<<<NE / 64, 256, 0, stream>>>(h, eidx, esh, ef, W1P, b1, W2P, b2, W3P, b3,
                                           agg, cnt);
  node_a<<<(NN + 255) / 256, 256, 0, stream>>>(h, A0, A1p, agg, cnt, outpre, stats);
  node_b<<<(NN * 80 + 255) / 256, 256, 0, stream>>>(outpre, stats, bnw0, bnb0, bnw1, h,
                                                    out);
}

// Round 4
// 223.431 us; speedup vs baseline: 17.0741x; 1.0503x over previous
//
#include <hip/hip_runtime.h>
#include <math.h>

#define NN 10000
#define NE 160000
#define NRBF 50
#define WNUM 2304
#define EPSV 1e-5f

#define A_P1 0.125f
#define A_P2 0.17677669529663687f
#define A_P3 0.125f
#define A_P4 0.17677669529663687f
#define INV_SQRT3 0.5773502691896258f
#define INV_SQRT_M0 0.17677669529663687f
#define INV_SQRT_M1 0.25f

typedef __attribute__((ext_vector_type(8))) short bf16x8;
typedef __attribute__((ext_vector_type(4))) float f32x4;
typedef __attribute__((ext_vector_type(4))) int i32x4;

#define MFMA16(a, b, c) __builtin_amdgcn_mfma_f32_16x16x32_bf16(a, b, c, 0, 0, 0)

__device__ __forceinline__ short f2bf(float x) {
  unsigned u = __float_as_uint(x);
  unsigned r = (u + 0x7fffu + ((u >> 16) & 1u)) >> 16;
  return (short)r;
}

// ---- weight prep: transpose + bf16 + fragment-order packing ----
// Packed layout per 16-col tile t: 1024 shorts = [chunk(2)][lane(64)][kk(8)].
// Lane l, chunk c holds B[row = t*16 + (l&15)][k = (l>>4)*8 + c*32 + kk].
__global__ void prep_weights(const float* __restrict__ W1, const float* __restrict__ W2,
                             const float* __restrict__ W3, short* __restrict__ W1P,
                             short* __restrict__ W2P, short* __restrict__ W3P) {
  int s = blockIdx.x * 256 + threadIdx.x;
  if (s < WNUM * 64) {
    int t = s >> 10, r = s & 1023;
    int ch = r >> 9, l = (r >> 3) & 63, kk = r & 7;
    int row = t * 16 + (l & 15);
    int k = ((l >> 4) << 3) + (ch << 5) + kk;
    W3P[s] = f2bf(W3[k * WNUM + row]);
  } else if (s < WNUM * 64 + 4096) {
    int s2 = s - WNUM * 64;
    int t = s2 >> 10, r = s2 & 1023;
    int ch = r >> 9, l = (r >> 3) & 63, kk = r & 7;
    int row = t * 16 + (l & 15);
    int k = ((l >> 4) << 3) + (ch << 5) + kk;
    W1P[s2] = f2bf(k < NRBF ? W1[k * 64 + row] : 0.f);
  } else if (s < WNUM * 64 + 8192) {
    int s2 = s - WNUM * 64 - 4096;
    int t = s2 >> 10, r = s2 & 1023;
    int ch = r >> 9, l = (r >> 3) & 63, kk = r & 7;
    int row = t * 16 + (l & 15);
    int k = ((l >> 4) << 3) + (ch << 5) + kk;
    W2P[s2] = f2bf(W2[k * 64 + row]);
  }
}

// v(local tile TL) for BOTH edge-groups: bias C-init + 2 MFMA each
#define TILE_V2(TL, V0, V1)                                   \
  {                                                           \
    const short* wb = WB + ((TL) << 10) + (l << 3);           \
    bf16x8 b0 = *(const bf16x8*)wb;                           \
    bf16x8 b1f = *(const bf16x8*)(wb + 512);                  \
    float bias = B3[((TL) << 4) + lr];                        \
    f32x4 d0 = {bias, bias, bias, bias};                      \
    f32x4 d1 = {bias, bias, bias, bias};                      \
    d0 = MFMA16(aA0, b0, d0);                                 \
    d1 = MFMA16(aB0, b0, d1);                                 \
    V0 = MFMA16(aA1, b1f, d0);                                \
    V1 = MFMA16(aB1, b1f, d1);                                \
  }

__global__ __launch_bounds__(256, 3) void edge_kernel(
    const float* __restrict__ h, const int* __restrict__ eidx,
    const float* __restrict__ esh, const float* __restrict__ ef,
    const short* __restrict__ W1P, const float* __restrict__ b1,
    const short* __restrict__ W2P, const float* __restrict__ b2,
    const short* __restrict__ W3P, const float* __restrict__ b3,
    float* __restrict__ agg, float* __restrict__ cnt) {
  __shared__ short buf0[64 * 72];  // efs -> h2s
  __shared__ short h1s[64 * 72];
  // coef block (24 KB): s0c[0..2047] = A_P3*s0[u], s1p[2048..5119] = A_P2*s1[u][i],
  // d4s[5120..6143]. Aliased as cross-wave reduce scratch after phase C.
  __shared__ float coef[6144];
  __shared__ float y0s[64], y1s[192];
  __shared__ float b1s[64], b2s[64];
  __shared__ int dsts[64];

  const int tid = threadIdx.x;
  const int e0 = blockIdx.x * 64;

  // ---- Phase A: staging ----
  for (int idx = tid; idx < 64 * 64; idx += 256) {
    int e = idx >> 6, k = idx & 63;
    float v = (k < NRBF) ? ef[(long)(e0 + e) * NRBF + k] : 0.f;
    buf0[e * 72 + k] = f2bf(v);
  }
  if (tid < 64) { b1s[tid] = b1[tid]; b2s[tid] = b2[tid]; }
  {
    int e = tid >> 2, q = tid & 3;
    int ge = e0 + e;
    int src = eidx[ge];
    float y0 = esh[ge * 4 + 0];
    float y1x = esh[ge * 4 + 1], y1y = esh[ge * 4 + 2], y1z = esh[ge * 4 + 3];
    const float* hs = h + (long)src * 80;
    for (int u = q; u < 32; u += 4) coef[u * 64 + e] = A_P3 * hs[u];
    for (int u = q; u < 16; u += 4) {
      float sx = hs[32 + u * 3], sy = hs[33 + u * 3], sz = hs[34 + u * 3];
      coef[2048 + (0 * 16 + u) * 64 + e] = A_P2 * sx;
      coef[2048 + (1 * 16 + u) * 64 + e] = A_P2 * sy;
      coef[2048 + (2 * 16 + u) * 64 + e] = A_P2 * sz;
      coef[5120 + u * 64 + e] = A_P4 * INV_SQRT3 * (sx * y1x + sy * y1y + sz * y1z);
    }
    if (q == 0) {
      y0s[e] = y0;
      y1s[e] = y1x; y1s[64 + e] = y1y; y1s[128 + e] = y1z;
      dsts[e] = eidx[NE + ge];
    }
  }
  __syncthreads();

  const int wid = tid >> 6, l = tid & 63;
  const int lr = l & 15, lg = l >> 4;

  // ---- MLP layer 1 ----
  {
    const int er = wid * 16;
    bf16x8 a0 = *(const bf16x8*)&buf0[(er + lr) * 72 + lg * 8];
    bf16x8 a1 = *(const bf16x8*)&buf0[(er + lr) * 72 + 32 + lg * 8];
#pragma unroll
    for (int jt = 0; jt < 4; ++jt) {
      const short* wb = W1P + (jt << 10) + (l << 3);
      bf16x8 b0 = *(const bf16x8*)wb;
      bf16x8 b1f = *(const bf16x8*)(wb + 512);
      float bias = b1s[jt * 16 + lr];
      f32x4 d = {bias, bias, bias, bias};
      d = MFMA16(a0, b0, d);
      d = MFMA16(a1, b1f, d);
#pragma unroll
      for (int r = 0; r < 4; ++r) {
        float x = d[r];
        x = x / (1.f + __expf(-x));
        h1s[(er + lg * 4 + r) * 72 + jt * 16 + lr] = f2bf(x);
      }
    }
  }
  __syncthreads();

  // ---- MLP layer 2 (h2 -> buf0) ----
  {
    const int er = wid * 16;
    bf16x8 a0 = *(const bf16x8*)&h1s[(er + lr) * 72 + lg * 8];
    bf16x8 a1 = *(const bf16x8*)&h1s[(er + lr) * 72 + 32 + lg * 8];
#pragma unroll
    for (int jt = 0; jt < 4; ++jt) {
      const short* wb = W2P + (jt << 10) + (l << 3);
      bf16x8 b0 = *(const bf16x8*)wb;
      bf16x8 b1f = *(const bf16x8*)(wb + 512);
      float bias = b2s[jt * 16 + lr];
      f32x4 d = {bias, bias, bias, bias};
      d = MFMA16(a0, b0, d);
      d = MFMA16(a1, b1f, d);
#pragma unroll
      for (int r = 0; r < 4; ++r) {
        float x = d[r];
        x = x / (1.f + __expf(-x));
        buf0[(er + lg * 4 + r) * 72 + jt * 16 + lr] = f2bf(x);
      }
    }
  }
  __syncthreads();

  // ---- Phase C: wave = (edge-pair gpair, tile-half) ----
  const int gpair = wid & 1, half = wid >> 1;
  const int g0 = gpair * 2;
  const int rowA = g0 * 16, rowB = (g0 + 1) * 16;
  const int r4A = rowA + lg * 4, r4B = rowB + lg * 4;

  bf16x8 aA0 = *(const bf16x8*)&buf0[(rowA + lr) * 72 + lg * 8];
  bf16x8 aA1 = *(const bf16x8*)&buf0[(rowA + lr) * 72 + 32 + lg * 8];
  bf16x8 aB0 = *(const bf16x8*)&buf0[(rowB + lr) * 72 + lg * 8];
  bf16x8 aB1 = *(const bf16x8*)&buf0[(rowB + lr) * 72 + 32 + lg * 8];
  f32x4 y0A = *(const f32x4*)&y0s[r4A];
  f32x4 y0B = *(const f32x4*)&y0s[r4B];

  const short* WB = W3P + ((half * 72) << 10);
  const float* B3 = b3 + half * 72 * 16;

  // m0 cols 0-15 / 16-31, m1 x/y/z for each of the 2 groups
  f32x4 s0A = {0,0,0,0}, s1A = {0,0,0,0}, s0B = {0,0,0,0}, s1B = {0,0,0,0};
  f32x4 mxA = {0,0,0,0}, myA = {0,0,0,0}, mzA = {0,0,0,0};
  f32x4 mxB = {0,0,0,0}, myB = {0,0,0,0}, mzB = {0,0,0,0};

  if (half == 0) {
    // region w1: u 0..31, local tiles 2u, 2u+1 ; m0 += s0c[u]*v (y0 factored)
#pragma unroll 2
    for (int u = 0; u < 32; ++u) {
      f32x4 cA = *(const f32x4*)&coef[u * 64 + r4A];
      f32x4 cB = *(const f32x4*)&coef[u * 64 + r4B];
      f32x4 vA0, vB0, vA1, vB1;
      TILE_V2(2 * u, vA0, vB0);
      TILE_V2(2 * u + 1, vA1, vB1);
#pragma unroll
      for (int r = 0; r < 4; ++r) {
        s0A[r] += cA[r] * vA0[r]; s1A[r] += cA[r] * vA1[r];
        s0B[r] += cB[r] * vB0[r]; s1B[r] += cB[r] * vB1[r];
      }
    }
#pragma unroll
    for (int r = 0; r < 4; ++r) {
      s0A[r] *= y0A[r]; s1A[r] *= y0A[r];
      s0B[r] *= y0B[r]; s1B[r] *= y0B[r];
    }
    // region w2 (u 0..7): local tiles 64+u ; m1[i] += s1p[i][u]*v (y0 factored)
#pragma unroll 2
    for (int u = 0; u < 8; ++u) {
      f32x4 v0, v1;
      TILE_V2(64 + u, v0, v1);
      f32x4 cxA = *(const f32x4*)&coef[2048 + (0 * 16 + u) * 64 + r4A];
      f32x4 cyA = *(const f32x4*)&coef[2048 + (1 * 16 + u) * 64 + r4A];
      f32x4 czA = *(const f32x4*)&coef[2048 + (2 * 16 + u) * 64 + r4A];
      f32x4 cxB = *(const f32x4*)&coef[2048 + (0 * 16 + u) * 64 + r4B];
      f32x4 cyB = *(const f32x4*)&coef[2048 + (1 * 16 + u) * 64 + r4B];
      f32x4 czB = *(const f32x4*)&coef[2048 + (2 * 16 + u) * 64 + r4B];
#pragma unroll
      for (int r = 0; r < 4; ++r) {
        mxA[r] += cxA[r] * v0[r]; myA[r] += cyA[r] * v0[r]; mzA[r] += czA[r] * v0[r];
        mxB[r] += cxB[r] * v1[r]; myB[r] += cyB[r] * v1[r]; mzB[r] += czB[r] * v1[r];
      }
    }
#pragma unroll
    for (int r = 0; r < 4; ++r) {
      mxA[r] *= y0A[r]; myA[r] *= y0A[r]; mzA[r] *= y0A[r];
      mxB[r] *= y0B[r]; myB[r] *= y0B[r]; mzB[r] *= y0B[r];
    }
  } else {
    // region w2 (u 8..15): local tiles u-8
#pragma unroll 2
    for (int u = 8; u < 16; ++u) {
      f32x4 v0, v1;
      TILE_V2(u - 8, v0, v1);
      f32x4 cxA = *(const f32x4*)&coef[2048 + (0 * 16 + u) * 64 + r4A];
      f32x4 cyA = *(const f32x4*)&coef[2048 + (1 * 16 + u) * 64 + r4A];
      f32x4 czA = *(const f32x4*)&coef[2048 + (2 * 16 + u) * 64 + r4A];
      f32x4 cxB = *(const f32x4*)&coef[2048 + (0 * 16 + u) * 64 + r4B];
      f32x4 cyB = *(const f32x4*)&coef[2048 + (1 * 16 + u) * 64 + r4B];
      f32x4 czB = *(const f32x4*)&coef[2048 + (2 * 16 + u) * 64 + r4B];
#pragma unroll
      for (int r = 0; r < 4; ++r) {
        mxA[r] += cxA[r] * v0[r]; myA[r] += cyA[r] * v0[r]; mzA[r] += czA[r] * v0[r];
        mxB[r] += cxB[r] * v1[r]; myB[r] += cyB[r] * v1[r]; mzB[r] += czB[r] * v1[r];
      }
    }
#pragma unroll
    for (int r = 0; r < 4; ++r) {
      mxA[r] *= y0A[r]; myA[r] *= y0A[r]; mzA[r] *= y0A[r];
      mxB[r] *= y0B[r]; myB[r] *= y0B[r]; mzB[r] *= y0B[r];
    }
    // region w3 (u 0..31): local tiles 8+u ; t3 += s0c[u]*v, fold with y1 after
    {
      f32x4 t3A = {0,0,0,0}, t3B = {0,0,0,0};
#pragma unroll 2
      for (int u = 0; u < 32; ++u) {
        f32x4 v0, v1;
        TILE_V2(8 + u, v0, v1);
        f32x4 cA = *(const f32x4*)&coef[u * 64 + r4A];
        f32x4 cB = *(const f32x4*)&coef[u * 64 + r4B];
#pragma unroll
        for (int r = 0; r < 4; ++r) {
          t3A[r] += cA[r] * v0[r];
          t3B[r] += cB[r] * v1[r];
        }
      }
      f32x4 yxA = *(const f32x4*)&y1s[0 + r4A], yxB = *(const f32x4*)&y1s[0 + r4B];
      f32x4 yyA = *(const f32x4*)&y1s[64 + r4A], yyB = *(const f32x4*)&y1s[64 + r4B];
      f32x4 yzA = *(const f32x4*)&y1s[128 + r4A], yzB = *(const f32x4*)&y1s[128 + r4B];
#pragma unroll
      for (int r = 0; r < 4; ++r) {
        mxA[r] += yxA[r] * t3A[r]; myA[r] += yyA[r] * t3A[r]; mzA[r] += yzA[r] * t3A[r];
        mxB[r] += yxB[r] * t3B[r]; myB[r] += yyB[r] * t3B[r]; mzB[r] += yzB[r] * t3B[r];
      }
    }
    // region w4 (up 0..15): local tiles 40+2up, 41+2up ; m0 += d4s[up]*v
#pragma unroll 2
    for (int up = 0; up < 16; ++up) {
      f32x4 cA = *(const f32x4*)&coef[5120 + up * 64 + r4A];
      f32x4 cB = *(const f32x4*)&coef[5120 + up * 64 + r4B];
      f32x4 vA0, vB0, vA1, vB1;
      TILE_V2(40 + 2 * up, vA0, vB0);
      TILE_V2(41 + 2 * up, vA1, vB1);
#pragma unroll
      for (int r = 0; r < 4; ++r) {
        s0A[r] += cA[r] * vA0[r]; s1A[r] += cA[r] * vA1[r];
        s0B[r] += cB[r] * vB0[r]; s1B[r] += cB[r] * vB1[r];
      }
    }
  }

  // ---- cross-wave reduce (half1 -> half0) over dead coef LDS, stride 41 ----
  __syncthreads();
  if (half == 1) {
    float* wr = coef + gpair * 2624 + l * 41;
#pragma unroll
    for (int r = 0; r < 4; ++r) {
      wr[0 + r] = s0A[r];  wr[4 + r] = s1A[r];
      wr[8 + r] = mxA[r];  wr[12 + r] = myA[r]; wr[16 + r] = mzA[r];
      wr[20 + r] = s0B[r]; wr[24 + r] = s1B[r];
      wr[28 + r] = mxB[r]; wr[32 + r] = myB[r]; wr[36 + r] = mzB[r];
    }
  }
  __syncthreads();
  if (half == 0) {
    const float* wr = coef + gpair * 2624 + l * 41;
#pragma unroll
    for (int r = 0; r < 4; ++r) {
      s0A[r] += wr[0 + r];  s1A[r] += wr[4 + r];
      mxA[r] += wr[8 + r];  myA[r] += wr[12 + r]; mzA[r] += wr[16 + r];
      s0B[r] += wr[20 + r]; s1B[r] += wr[24 + r];
      mxB[r] += wr[28 + r]; myB[r] += wr[32 + r]; mzB[r] += wr[36 + r];
    }
    i32x4 ddA = *(const i32x4*)&dsts[r4A];
    i32x4 ddB = *(const i32x4*)&dsts[r4B];
#pragma unroll
    for (int r = 0; r < 4; ++r) {
      float* base = agg + (long)ddA[r] * 80;
      atomicAdd(base + lr, s0A[r]);
      atomicAdd(base + 16 + lr, s1A[r]);
      atomicAdd(base + 32 + lr * 3 + 0, mxA[r]);
      atomicAdd(base + 32 + lr * 3 + 1, myA[r]);
      atomicAdd(base + 32 + lr * 3 + 2, mzA[r]);
    }
#pragma unroll
    for (int r = 0; r < 4; ++r) {
      float* base = agg + (long)ddB[r] * 80;
      atomicAdd(base + lr, s0B[r]);
      atomicAdd(base + 16 + lr, s1B[r]);
      atomicAdd(base + 32 + lr * 3 + 0, mxB[r]);
      atomicAdd(base + 32 + lr * 3 + 1, myB[r]);
      atomicAdd(base + 32 + lr * 3 + 2, mzB[r]);
    }
  }
  if (tid < 64) atomicAdd(cnt + dsts[tid], 1.0f);
}

__global__ __launch_bounds__(256) void node_a(
    const float* __restrict__ h, const float* __restrict__ A0,
    const float* __restrict__ A1p, const float* __restrict__ agg,
    const float* __restrict__ cnt, float* __restrict__ outpre,
    float* __restrict__ stats) {
  __shared__ float redw[4][80];
  const int tid = threadIdx.x;
  const int wid = tid >> 6, l = tid & 63;
  const int n = blockIdx.x * 256 + tid;
  float x0[32], x1[48];
#pragma unroll
  for (int w = 0; w < 32; w++) x0[w] = 0.f;
#pragma unroll
  for (int c = 0; c < 48; c++) x1[c] = 0.f;
  if (n < NN) {
    const float* hr = h + (long)n * 80;
    const float* ar = agg + (long)n * 80;
    float inv = 1.f / fmaxf(cnt[n], 1.f);
#pragma unroll 1
    for (int u = 0; u < 32; u++) {
      float hu = hr[u];
#pragma unroll
      for (int w = 0; w < 32; w++) x0[w] += hu * A0[u * 32 + w];
    }
#pragma unroll
    for (int w = 0; w < 32; w++) x0[w] = x0[w] * INV_SQRT_M0 + ar[w] * inv;
#pragma unroll 1
    for (int u = 0; u < 16; u++) {
      float a = hr[32 + u * 3], b_ = hr[33 + u * 3], c_ = hr[34 + u * 3];
#pragma unroll
      for (int w = 0; w < 16; w++) {
        float Aw = A1p[u * 16 + w];
        x1[w * 3 + 0] += a * Aw;
        x1[w * 3 + 1] += b_ * Aw;
        x1[w * 3 + 2] += c_ * Aw;
      }
    }
#pragma unroll
    for (int c = 0; c < 48; c++) x1[c] = x1[c] * INV_SQRT_M1 + ar[32 + c] * inv;
    float* opr = outpre + (long)n * 80;
#pragma unroll
    for (int w = 0; w < 32; w++) opr[w] = x0[w];
#pragma unroll
    for (int c = 0; c < 48; c++) opr[32 + c] = x1[c];
  }
#pragma unroll 1
  for (int c = 0; c < 32; ++c) {
    float s = x0[c];
#pragma unroll
    for (int m = 32; m >= 1; m >>= 1) s += __shfl_xor(s, m, 64);
    if (l == 0) redw[wid][c] = s;
  }
#pragma unroll 1
  for (int c = 0; c < 32; ++c) {
    float v = x0[c];
    float s = v * v;
#pragma unroll
    for (int m = 32; m >= 1; m >>= 1) s += __shfl_xor(s, m, 64);
    if (l == 0) redw[wid][32 + c] = s;
  }
#pragma unroll 1
  for (int u = 0; u < 16; ++u) {
    float s = x1[u * 3] * x1[u * 3] + x1[u * 3 + 1] * x1[u * 3 + 1] +
              x1[u * 3 + 2] * x1[u * 3 + 2];
#pragma unroll
    for (int m = 32; m >= 1; m >>= 1) s += __shfl_xor(s, m, 64);
    if (l == 0) redw[wid][64 + u] = s;
  }
  __syncthreads();
  if (tid < 80)
    atomicAdd(&stats[tid],
              redw[0][tid] + redw[1][tid] + redw[2][tid] + redw[3][tid]);
}

__global__ void node_b(const float* __restrict__ outpre, const float* __restrict__ stats,
                       const float* __restrict__ bnw0, const float* __restrict__ bnb0,
                       const float* __restrict__ bnw1, const float* __restrict__ h,
                       float* __restrict__ out) {
  int idx = blockIdx.x * 256 + threadIdx.x;
  if (idx >= NN * 80) return;
  int c = idx % 80;
  float v = outpre[idx];
  const float invN = 1.f / NN;
  float o;
  if (c < 32) {
    float mu = stats[c] * invN;
    float var = stats[32 + c] * invN - mu * mu;
    o = (v - mu) * rsqrtf(var + EPSV) * bnw0[c] + bnb0[c];
  } else {
    int u = (c - 32) / 3;
    float nr = stats[64 + u] * invN;
    o = v * rsqrtf(nr + EPSV) * bnw1[u];
  }
  out[idx] = o + h[idx];
}

extern "C" void kernel_launch(void* const* d_in, const int* in_sizes, int n_in,
                              void* d_out, int out_size, void* d_ws, size_t ws_size,
                              hipStream_t stream) {
  const float* h    = (const float*)d_in[0];
  const int*   eidx = (const int*)d_in[1];
  const float* esh  = (const float*)d_in[2];
  const float* ef   = (const float*)d_in[3];
  const float* W1   = (const float*)d_in[4];
  const float* b1   = (const float*)d_in[5];
  const float* W2   = (const float*)d_in[6];
  const float* b2   = (const float*)d_in[7];
  const float* W3   = (const float*)d_in[8];
  const float* b3   = (const float*)d_in[9];
  const float* A0   = (const float*)d_in[10];
  const float* A1p  = (const float*)d_in[11];
  const float* bnw0 = (const float*)d_in[12];
  const float* bnb0 = (const float*)d_in[13];
  const float* bnw1 = (const float*)d_in[14];
  float* out = (float*)d_out;

  float* ws = (float*)d_ws;
  float* agg    = ws;             // 800000
  float* cnt    = ws + 800000;    // 10000
  float* stats  = ws + 810000;    // 80
  float* outpre = ws + 810080;    // 800000
  short* W3P    = (short*)(ws + 1610080);  // 147456 shorts
  short* W1P    = W3P + WNUM * 64;         // 4096 shorts
  short* W2P    = W1P + 4096;              // 4096 shorts

  hipMemsetAsync(agg, 0, (size_t)810080 * sizeof(float), stream);

  prep_weights<<<(WNUM * 64 + 8192 + 255) / 256, 256, 0, stream>>>(W1, W2, W3, W1P,
                                                                   W2P, W3P);
  edge_kernel<<<NE / 64, 256, 0, stream>>>(h, eidx, esh, ef, W1P, b1, W2P, b2, W3P, b3,
                                           agg, cnt);
  node_a<<<(NN + 255) / 256, 256, 0, stream>>>(h, A0, A1p, agg, cnt, outpre, stats);
  node_b<<<(NN * 80 + 255) / 256, 256, 0, stream>>>(outpre, stats, bnw0, bnb0, bnw1, h,
                                                    out);
}